// Round 1
// baseline (605.371 us; speedup 1.0000x reference)
//
#include <hip/hip_runtime.h>

// ---------------------------------------------------------------------------
// 2-layer LSTM (Keras gate order i,f,g,o) + Dense(27) + softmax, fp32.
// B=32768, T=21, F=126, U=8.
//
// Layout: block = 256 threads = 4 waves = 64 samples.
//   lane (0..63)  = sample within block
//   wave (0..3)   = gate group (i,f,g,o), i.e. columns [8w, 8w+8) of the
//                   4U=32-wide pre-activation z.
// Weights are read at wave-uniform addresses (wave id via readfirstlane) so
// they go through the scalar pipe (s_load) and cost no VMEM/LDS bandwidth.
// x is staged into LDS coalesced once per timestep. Gate pre-activations are
// exchanged via LDS (3 barriers/timestep); h/c state is replicated in all 4
// waves' registers so no extra barrier is needed for the recurrent matmuls.
// ---------------------------------------------------------------------------

namespace {
constexpr int T_   = 21;
constexpr int FIN  = 126;
constexpr int U_   = 8;
constexpr int NC   = 27;
constexpr int BS   = 64;    // samples per block
constexpr int NTH  = 256;   // threads per block (4 waves)
constexpr int ROW  = T_ * FIN;  // 2646 floats per sample
}

__device__ __forceinline__ float sigm(float x) {
  // 1/(1+e^-x); saturates correctly at +-inf (exp->inf -> 0, exp->0 -> 1)
  return __builtin_amdgcn_rcpf(1.0f + __expf(-x));
}
__device__ __forceinline__ float tanh_f(float x) {
  // exact identity: tanh(x) = 1 - 2/(1+e^{2x}); stable at both tails
  return 1.0f - 2.0f * __builtin_amdgcn_rcpf(1.0f + __expf(2.0f * x));
}

__global__ __launch_bounds__(NTH, 2) void lstm2_dense(
    const float* __restrict__ X,
    const float* __restrict__ W1k, const float* __restrict__ W1r,
    const float* __restrict__ b1,
    const float* __restrict__ W2k, const float* __restrict__ W2r,
    const float* __restrict__ b2,
    const float* __restrict__ Wd, const float* __restrict__ bd,
    float* __restrict__ out)
{
  __shared__ __align__(16) float xbuf[BS * FIN];   // [s][f]       32256 B
  __shared__ __align__(16) float zb1[4 * U_ * BS]; // [col][s]      8192 B
  __shared__ __align__(16) float zb2[4 * U_ * BS]; // [col][s]      8192 B

  const int tid = threadIdx.x;
  const int sl  = tid & 63;                                   // sample lane
  const int wv  = __builtin_amdgcn_readfirstlane(tid >> 6);   // gate/wave id
  const int blk = blockIdx.x;

  // wave-uniform weight slice pointers: columns [8wv, 8wv+8)
  const float4* W1k4 = reinterpret_cast<const float4*>(W1k) + 2 * wv; // [f*8+{0,1}]
  const float4* W1r4 = reinterpret_cast<const float4*>(W1r) + 2 * wv; // [k*8+{0,1}]
  const float4* W2k4 = reinterpret_cast<const float4*>(W2k) + 2 * wv;
  const float4* W2r4 = reinterpret_cast<const float4*>(W2r) + 2 * wv;
  const float4  b1a = reinterpret_cast<const float4*>(b1)[2 * wv];
  const float4  b1b = reinterpret_cast<const float4*>(b1)[2 * wv + 1];
  const float4  b2a = reinterpret_cast<const float4*>(b2)[2 * wv];
  const float4  b2b = reinterpret_cast<const float4*>(b2)[2 * wv + 1];

  float c1[U_], h1[U_], c2[U_], h2[U_];
  #pragma unroll
  for (int u = 0; u < U_; ++u) { c1[u] = 0.f; h1[u] = 0.f; c2[u] = 0.f; h2[u] = 0.f; }

  const float* xbase = X + (size_t)blk * BS * ROW;

  for (int t = 0; t < T_; ++t) {
    // ---- stage x[:, t, :] into LDS (coalesced: 504 B contiguous per row) ----
    #pragma unroll
    for (int k = 0; k < 16; ++k) {
      int j = tid + k * NTH;            // j over BS*63 float2 elements
      if (j < BS * 63) {
        int s = j / 63;
        int q = j - s * 63;
        float2 v = *reinterpret_cast<const float2*>(
            xbase + (size_t)s * ROW + t * FIN + 2 * q);
        *reinterpret_cast<float2*>(&xbuf[s * FIN + 2 * q]) = v;
      }
    }
    __syncthreads();

    // ---- z1 slice: b1 + x_t @ W1k  (this wave's 8 columns) ----
    float4 za = b1a, zb = b1b;
    {
      const float2* xr = reinterpret_cast<const float2*>(&xbuf[sl * FIN]);
      #pragma unroll 3
      for (int q = 0; q < 63; ++q) {
        float2 xv = xr[q];
        float4 wa0 = W1k4[(2 * q) * 8];
        float4 wb0 = W1k4[(2 * q) * 8 + 1];
        float4 wa1 = W1k4[(2 * q + 1) * 8];
        float4 wb1 = W1k4[(2 * q + 1) * 8 + 1];
        za.x += xv.x * wa0.x; za.y += xv.x * wa0.y; za.z += xv.x * wa0.z; za.w += xv.x * wa0.w;
        zb.x += xv.x * wb0.x; zb.y += xv.x * wb0.y; zb.z += xv.x * wb0.z; zb.w += xv.x * wb0.w;
        za.x += xv.y * wa1.x; za.y += xv.y * wa1.y; za.z += xv.y * wa1.z; za.w += xv.y * wa1.w;
        zb.x += xv.y * wb1.x; zb.y += xv.y * wb1.y; zb.z += xv.y * wb1.z; zb.w += xv.y * wb1.w;
      }
    }
    // ---- + h1_{t-1} @ W1r (h1 replicated in registers) ----
    #pragma unroll
    for (int k = 0; k < U_; ++k) {
      float hv = h1[k];
      float4 wa = W1r4[k * 8];
      float4 wb = W1r4[k * 8 + 1];
      za.x += hv * wa.x; za.y += hv * wa.y; za.z += hv * wa.z; za.w += hv * wa.w;
      zb.x += hv * wb.x; zb.y += hv * wb.y; zb.z += hv * wb.z; zb.w += hv * wb.w;
    }
    {
      float* zp = &zb1[(8 * wv) * BS + sl];      // lane-consecutive: no conflicts
      zp[0 * BS] = za.x; zp[1 * BS] = za.y; zp[2 * BS] = za.z; zp[3 * BS] = za.w;
      zp[4 * BS] = zb.x; zp[5 * BS] = zb.y; zp[6 * BS] = zb.z; zp[7 * BS] = zb.w;
    }
    __syncthreads();

    // ---- LSTM1 state update (replicated in every wave; avoids a barrier) ----
    #pragma unroll
    for (int u = 0; u < U_; ++u) {
      float zi = zb1[u * BS + sl];
      float zf = zb1[(U_ + u) * BS + sl];
      float zg = zb1[(2 * U_ + u) * BS + sl];
      float zo = zb1[(3 * U_ + u) * BS + sl];
      float iv = sigm(zi), fv = sigm(zf), gv = tanh_f(zg), ov = sigm(zo);
      float cn = fv * c1[u] + iv * gv;
      c1[u] = cn;
      h1[u] = ov * tanh_f(cn);
    }

    // ---- z2 slice: b2 + h1_t @ W2k + h2_{t-1} @ W2r ----
    za = b2a; zb = b2b;
    #pragma unroll
    for (int k = 0; k < U_; ++k) {
      float hv = h1[k];
      float4 wa = W2k4[k * 8];
      float4 wb = W2k4[k * 8 + 1];
      za.x += hv * wa.x; za.y += hv * wa.y; za.z += hv * wa.z; za.w += hv * wa.w;
      zb.x += hv * wb.x; zb.y += hv * wb.y; zb.z += hv * wb.z; zb.w += hv * wb.w;
    }
    #pragma unroll
    for (int k = 0; k < U_; ++k) {
      float hv = h2[k];
      float4 wa = W2r4[k * 8];
      float4 wb = W2r4[k * 8 + 1];
      za.x += hv * wa.x; za.y += hv * wa.y; za.z += hv * wa.z; za.w += hv * wa.w;
      zb.x += hv * wb.x; zb.y += hv * wb.y; zb.z += hv * wb.z; zb.w += hv * wb.w;
    }
    {
      float* zp = &zb2[(8 * wv) * BS + sl];
      zp[0 * BS] = za.x; zp[1 * BS] = za.y; zp[2 * BS] = za.z; zp[3 * BS] = za.w;
      zp[4 * BS] = zb.x; zp[5 * BS] = zb.y; zp[6 * BS] = zb.z; zp[7 * BS] = zb.w;
    }
    __syncthreads();

    // ---- LSTM2 state update (replicated) ----
    #pragma unroll
    for (int u = 0; u < U_; ++u) {
      float zi = zb2[u * BS + sl];
      float zf = zb2[(U_ + u) * BS + sl];
      float zg = zb2[(2 * U_ + u) * BS + sl];
      float zo = zb2[(3 * U_ + u) * BS + sl];
      float iv = sigm(zi), fv = sigm(zf), gv = tanh_f(zg), ov = sigm(zo);
      float cn = fv * c2[u] + iv * gv;
      c2[u] = cn;
      h2[u] = ov * tanh_f(cn);
    }
  }

  // ---- Dense(27) + softmax on h2[T-1] (computed redundantly; wave 0 writes) ----
  float logits[NC];
  float m = -1e30f;
  #pragma unroll
  for (int c = 0; c < NC; ++c) {
    float acc = bd[c];
    #pragma unroll
    for (int k = 0; k < U_; ++k) acc += h2[k] * Wd[k * NC + c];
    logits[c] = acc;
    m = fmaxf(m, acc);
  }
  float ssum = 0.f;
  #pragma unroll
  for (int c = 0; c < NC; ++c) {
    float e = __expf(logits[c] - m);
    logits[c] = e;
    ssum += e;
  }
  float inv = 1.0f / ssum;
  if (wv == 0) {
    #pragma unroll
    for (int c = 0; c < NC; ++c) zb1[sl * NC + c] = logits[c] * inv;
  }
  __syncthreads();
  {
    float* oblk = out + (size_t)blk * BS * NC;
    #pragma unroll
    for (int k = 0; k < 7; ++k) {
      int j = tid + k * NTH;
      if (j < BS * NC) oblk[j] = zb1[j];   // coalesced store
    }
  }
}

extern "C" void kernel_launch(void* const* d_in, const int* in_sizes, int n_in,
                              void* d_out, int out_size, void* d_ws, size_t ws_size,
                              hipStream_t stream) {
  const float* X   = (const float*)d_in[0];
  const float* W1k = (const float*)d_in[1];
  const float* W1r = (const float*)d_in[2];
  const float* b1  = (const float*)d_in[3];
  const float* W2k = (const float*)d_in[4];
  const float* W2r = (const float*)d_in[5];
  const float* b2  = (const float*)d_in[6];
  const float* Wd  = (const float*)d_in[7];
  const float* bd  = (const float*)d_in[8];
  float* out = (float*)d_out;

  const int B = in_sizes[0] / ROW;   // 32768
  dim3 grid(B / BS), block(NTH);
  lstm2_dense<<<grid, block, 0, stream>>>(X, W1k, W1r, b1, W2k, W2r, b2,
                                          Wd, bd, out);
}